// Round 12
// baseline (237.166 us; speedup 1.0000x reference)
//
#include <hip/hip_runtime.h>

// ROUND 12 = A/B DIAGNOSTIC (round 9 style — the only method that's produced
// information). Five interventions (MLP, intensity, LDS, lane-local reduce,
// occupancy) all leave main ~20-24us vs 7-9us pipe model. Hypotheses left:
//   H1: within-wave MFMA->tree serialization (MFMA result latency >> model)
//   H2: attribution wrong — main is fast, aux kernels + dispatch gaps ~20us
// REP=8 repeats (staging hoisted, running-max across reps, opaque asm offset,
// atomics deferred to after rep loop) make BOTH variants visible in top-5:
//   diag_imm : round-10 structure (4 q-tiles, tree right after MFMA)
//   diag_pipe: software-pipelined (issue MFMAs for tile t before reducing t-1)
// Closure: total - diag_imm - diag_pipe = aux+gaps (tests H2).
// bf16 hi/lo rep + swapped-operand MFMA (validated rounds 3-11, absmax 0).

#define NPTS    8192
#define BATCH   4
#define NSLOTS  (2 * BATCH * NPTS) // 65536
#define REP     8

typedef __attribute__((ext_vector_type(8))) short short8v;
typedef __attribute__((ext_vector_type(16))) float f32x16;

__device__ __forceinline__ unsigned enc_f32(float f) {
  unsigned u = __float_as_uint(f);
  return (u & 0x80000000u) ? ~u : (u | 0x80000000u);
}
__device__ __forceinline__ float dec_f32(unsigned u) {
  u = (u & 0x80000000u) ? (u ^ 0x80000000u) : ~u;
  return __uint_as_float(u);
}
__device__ __forceinline__ unsigned short f2bf(float x) {   // RNE bf16
  unsigned u = __float_as_uint(x);
  unsigned r = u + 0x7FFFu + ((u >> 16) & 1u);
  return (unsigned short)(r >> 16);
}
__device__ __forceinline__ float bf2f(unsigned short b) {
  return __uint_as_float((unsigned)b << 16);
}

// Tiled rep: element offset for point j (batch b), k-half h:
//   b*131072 + (j>>5)*512 + h*256 + (j&31)*8   [shorts]
__global__ __launch_bounds__(256) void prep(
    const float* __restrict__ c1, const float* __restrict__ c2,
    unsigned short* __restrict__ a1, unsigned short* __restrict__ a2,
    unsigned short* __restrict__ b1, unsigned short* __restrict__ b2,
    unsigned* __restrict__ rowbuf) {
  int pid = blockIdx.x * 256 + threadIdx.x;
  if (pid >= BATCH * NPTS) return;
  rowbuf[pid] = 0u;
  rowbuf[pid + BATCH * NPTS] = 0u;
  const unsigned short one = 0x3F80u, negone = 0xBF80u;
  int b = pid >> 13, j = pid & (NPTS - 1);
  size_t off0 = (size_t)b * 131072 + (size_t)(j >> 5) * 512 + (size_t)(j & 31) * 8;
  const float* cs[2] = {c1, c2};
  unsigned short* as[2] = {a1, a2};
  unsigned short* bs[2] = {b1, b2};
  #pragma unroll
  for (int c = 0; c < 2; ++c) {
    float x = cs[c][pid * 3 + 0], y = cs[c][pid * 3 + 1], z = cs[c][pid * 3 + 2];
    unsigned short xh = f2bf(x), yh = f2bf(y), zh = f2bf(z);
    unsigned short xl = f2bf(x - bf2f(xh)), yl = f2bf(y - bf2f(yh)),
                   zl = f2bf(z - bf2f(zh));
    float hn = 0.5f * (x * x + y * y + z * z);
    unsigned short hh = f2bf(hn), hl = f2bf(hn - bf2f(hh));
    unsigned short va[16] = {xh, yh, zh, xl, yl, zl, xh, yh, zh,
                             hh, hl, one, one, 0, 0, 0};
    unsigned short nh = hh ^ 0x8000u, nl = hl ^ 0x8000u;
    unsigned short vb[16] = {xh, yh, zh, xh, yh, zh, xl, yl, zl,
                             negone, negone, nh, nl, 0, 0, 0};
    *(uint4*)(as[c] + off0)       = *(const uint4*)&va[0];
    *(uint4*)(as[c] + off0 + 256) = *(const uint4*)&va[8];
    *(uint4*)(bs[c] + off0)       = *(const uint4*)&vb[0];
    *(uint4*)(bs[c] + off0 + 256) = *(const uint4*)&vb[8];
  }
}

__device__ __forceinline__ float tree17(const f32x16& c, float m) {
  float t0 = fmaxf(fmaxf(c[0],  c[1]),  c[2]);    // v_max3_f32
  float t1 = fmaxf(fmaxf(c[3],  c[4]),  c[5]);
  float t2 = fmaxf(fmaxf(c[6],  c[7]),  c[8]);
  float t3 = fmaxf(fmaxf(c[9],  c[10]), c[11]);
  float t4 = fmaxf(fmaxf(c[12], c[13]), c[14]);
  float u0 = fmaxf(fmaxf(t0, t1), t2);
  float u1 = fmaxf(fmaxf(t3, t4), c[15]);
  return fmaxf(fmaxf(u0, u1), m);
}

// Variant IMM: round-10 structure. grid = 2 x 4 x 16(ig:512q) x 8(jc) = 1024
// blocks x 4 waves; wave = 4 q-tiles; JCHUNK=1024 (33 KB LDS).
__global__ __launch_bounds__(256, 4) void diag_imm(
    const unsigned short* __restrict__ a1, const unsigned short* __restrict__ a2,
    const unsigned short* __restrict__ b1, const unsigned short* __restrict__ b2,
    unsigned* __restrict__ rowbuf) {
  __shared__ __align__(16) unsigned short sB[(1024 + 32) * 16];  // 33 KB

  int bid = blockIdx.x;
  int jc  = bid & 7;
  int ig  = (bid >> 3) & 15;
  int b   = (bid >> 7) & 3;
  int dir = bid >> 9;

  const unsigned short* A = dir ? a2 : a1;
  const unsigned short* B = dir ? b1 : b2;

  int wave = threadIdx.x >> 6;
  int lane = threadIdx.x & 63;
  int p = lane & 31, h = lane >> 5;

  {
    const char* gb = (const char*)B + (size_t)b * 262144 + (size_t)jc * 32768
                     + wave * 8192 + lane * 16;
    char* lb = (char*)sB + wave * 8192;
    #pragma unroll
    for (int k = 0; k < 8; ++k) {
      __builtin_amdgcn_global_load_lds(
          (const __attribute__((address_space(1))) unsigned int*)(gb + k * 1024),
          (__attribute__((address_space(3))) unsigned int*)(lb + k * 1024),
          16, 0, 0);
    }
  }

  int q0 = ig * 512 + wave * 128;
  const unsigned short* Ap =
      A + (size_t)b * 131072 + (size_t)(q0 >> 5) * 512 + h * 256 + p * 8;
  short8v aq0 = *(const short8v*)(const void*)(Ap);
  short8v aq1 = *(const short8v*)(const void*)(Ap + 512);
  short8v aq2 = *(const short8v*)(const void*)(Ap + 1024);
  short8v aq3 = *(const short8v*)(const void*)(Ap + 1536);

  f32x16 zero;
  #pragma unroll
  for (int i = 0; i < 16; ++i) zero[i] = 0.0f;
  float m0 = -3.4e38f, m1 = -3.4e38f, m2 = -3.4e38f, m3 = -3.4e38f;

  __syncthreads();

  #pragma unroll 1
  for (int rep = 0; rep < REP; ++rep) {
    int off = 0;
    asm volatile("" : "+v"(off));   // opaque per-rep offset: defeats CSE
    const char* sp = (const char*)sB + lane * 16 + off;
    short8v bt = *(const short8v*)(const void*)(sp);
    #pragma unroll 1
    for (int jt = 0; jt < 32; ++jt) {
      short8v btn = *(const short8v*)(const void*)(sp + (size_t)(jt + 1) * 1024);
      f32x16 c0 = __builtin_amdgcn_mfma_f32_32x32x16_bf16(bt, aq0, zero, 0, 0, 0);
      f32x16 c1 = __builtin_amdgcn_mfma_f32_32x32x16_bf16(bt, aq1, zero, 0, 0, 0);
      f32x16 c2 = __builtin_amdgcn_mfma_f32_32x32x16_bf16(bt, aq2, zero, 0, 0, 0);
      f32x16 c3 = __builtin_amdgcn_mfma_f32_32x32x16_bf16(bt, aq3, zero, 0, 0, 0);
      m0 = tree17(c0, m0);   // immediate consumption (round-10 pattern)
      m1 = tree17(c1, m1);
      m2 = tree17(c2, m2);
      m3 = tree17(c3, m3);
      bt = btn;
    }
  }

  m0 = fmaxf(m0, __shfl_xor(m0, 32, 64));
  m1 = fmaxf(m1, __shfl_xor(m1, 32, 64));
  m2 = fmaxf(m2, __shfl_xor(m2, 32, 64));
  m3 = fmaxf(m3, __shfl_xor(m3, 32, 64));

  unsigned* rb = rowbuf + ((size_t)dir * BATCH + b) * NPTS + q0;
  if (lane < 32) {
    atomicMax(rb + p,      enc_f32(m0));
    atomicMax(rb + 32 + p, enc_f32(m1));
    atomicMax(rb + 64 + p, enc_f32(m2));
    atomicMax(rb + 96 + p, enc_f32(m3));
  }
}

// Variant PIPE: software-pipelined. grid = 2 x 4 x 32(ig:256q) x 16(jc) =
// 4096 blocks x 4 waves; wave = 2 q-tiles; JCHUNK=512 (16 KB LDS).
// MFMAs for tile t issue BEFORE trees of tile t-1 (even/odd static regs).
__global__ __launch_bounds__(256, 4) void diag_pipe(
    const unsigned short* __restrict__ a1, const unsigned short* __restrict__ a2,
    const unsigned short* __restrict__ b1, const unsigned short* __restrict__ b2,
    unsigned* __restrict__ rowbuf) {
  __shared__ __align__(16) unsigned short sB[512 * 16];  // 16 KB

  int bid = blockIdx.x;
  int jc  = bid & 15;
  int ig  = (bid >> 4) & 31;
  int b   = (bid >> 9) & 3;
  int dir = bid >> 11;

  const unsigned short* A = dir ? a2 : a1;
  const unsigned short* B = dir ? b1 : b2;

  int wave = threadIdx.x >> 6;
  int lane = threadIdx.x & 63;
  int p = lane & 31, h = lane >> 5;

  {
    const char* gb = (const char*)B + (size_t)b * 262144 + (size_t)jc * 16384
                     + wave * 4096 + lane * 16;
    char* lb = (char*)sB + wave * 4096;
    #pragma unroll
    for (int k = 0; k < 4; ++k) {
      __builtin_amdgcn_global_load_lds(
          (const __attribute__((address_space(1))) unsigned int*)(gb + k * 1024),
          (__attribute__((address_space(3))) unsigned int*)(lb + k * 1024),
          16, 0, 0);
    }
  }

  int q0 = ig * 256 + wave * 64;
  const unsigned short* Ap =
      A + (size_t)b * 131072 + (size_t)(q0 >> 5) * 512 + h * 256 + p * 8;
  short8v aq0 = *(const short8v*)(const void*)(Ap);
  short8v aq1 = *(const short8v*)(const void*)(Ap + 512);

  f32x16 zero;
  #pragma unroll
  for (int i = 0; i < 16; ++i) zero[i] = 0.0f;
  float m0 = -3.4e38f, m1 = -3.4e38f;

  __syncthreads();

  #pragma unroll 1
  for (int rep = 0; rep < REP; ++rep) {
    int off = 0;
    asm volatile("" : "+v"(off));
    const char* sp = (const char*)sB + lane * 16 + off;

    short8v t0 = *(const short8v*)(const void*)(sp);
    f32x16 cA0 = __builtin_amdgcn_mfma_f32_32x32x16_bf16(t0, aq0, zero, 0, 0, 0);
    f32x16 cA1 = __builtin_amdgcn_mfma_f32_32x32x16_bf16(t0, aq1, zero, 0, 0, 0);
    #pragma unroll 1
    for (int jt = 1; jt < 15; jt += 2) {
      short8v tO = *(const short8v*)(const void*)(sp + (size_t)jt * 1024);
      f32x16 cB0 = __builtin_amdgcn_mfma_f32_32x32x16_bf16(tO, aq0, zero, 0, 0, 0);
      f32x16 cB1 = __builtin_amdgcn_mfma_f32_32x32x16_bf16(tO, aq1, zero, 0, 0, 0);
      m0 = tree17(cA0, m0);          // reduce PREVIOUS while current in flight
      m1 = tree17(cA1, m1);
      short8v tE = *(const short8v*)(const void*)(sp + (size_t)(jt + 1) * 1024);
      cA0 = __builtin_amdgcn_mfma_f32_32x32x16_bf16(tE, aq0, zero, 0, 0, 0);
      cA1 = __builtin_amdgcn_mfma_f32_32x32x16_bf16(tE, aq1, zero, 0, 0, 0);
      m0 = tree17(cB0, m0);
      m1 = tree17(cB1, m1);
    }
    {
      short8v tL = *(const short8v*)(const void*)(sp + (size_t)15 * 1024);
      f32x16 cB0 = __builtin_amdgcn_mfma_f32_32x32x16_bf16(tL, aq0, zero, 0, 0, 0);
      f32x16 cB1 = __builtin_amdgcn_mfma_f32_32x32x16_bf16(tL, aq1, zero, 0, 0, 0);
      m0 = tree17(cA0, m0);
      m1 = tree17(cA1, m1);
      m0 = tree17(cB0, m0);
      m1 = tree17(cB1, m1);
    }
  }

  m0 = fmaxf(m0, __shfl_xor(m0, 32, 64));
  m1 = fmaxf(m1, __shfl_xor(m1, 32, 64));

  unsigned* rb = rowbuf + ((size_t)dir * BATCH + b) * NPTS + q0;
  if (lane < 32) {
    atomicMax(rb + p,      enc_f32(m0));
    atomicMax(rb + 32 + p, enc_f32(m1));
  }
}

__global__ __launch_bounds__(1024) void loss_final(
    const unsigned* __restrict__ rowbuf, float* __restrict__ out) {
  int tid = threadIdx.x;
  const uint4* rb4 = (const uint4*)rowbuf;
  float s = 0.0f;
  #pragma unroll
  for (int k = 0; k < NSLOTS / 4096; ++k) {
    uint4 u = rb4[k * 1024 + tid];
    s = fmaf(-2.0f, dec_f32(u.x), s);
    s = fmaf(-2.0f, dec_f32(u.y), s);
    s = fmaf(-2.0f, dec_f32(u.z), s);
    s = fmaf(-2.0f, dec_f32(u.w), s);
  }
  #pragma unroll
  for (int off = 32; off > 0; off >>= 1) s += __shfl_down(s, off, 64);
  __shared__ float wsum[16];
  if ((tid & 63) == 0) wsum[tid >> 6] = s;
  __syncthreads();
  if (tid == 0) {
    float t = 0.0f;
    #pragma unroll
    for (int w2 = 0; w2 < 16; ++w2) t += wsum[w2];
    out[0] = t;
  }
}

extern "C" void kernel_launch(void* const* d_in, const int* in_sizes, int n_in,
                              void* d_out, int out_size, void* d_ws, size_t ws_size,
                              hipStream_t stream) {
  const float* c1 = (const float*)d_in[0];
  const float* c2 = (const float*)d_in[1];
  float* out = (float*)d_out;

  char* ws = (char*)d_ws;
  unsigned* rowbuf = (unsigned*)ws;                          // 65536 u32 = 256 KB
  unsigned short* a1 = (unsigned short*)(ws + (size_t)NSLOTS * 4);
  unsigned short* a2 = a1 + (size_t)BATCH * NPTS * 16;       // 1 MB each
  unsigned short* b1 = a2 + (size_t)BATCH * NPTS * 16;
  unsigned short* b2 = b1 + (size_t)BATCH * NPTS * 16;

  prep<<<(BATCH * NPTS) / 256, 256, 0, stream>>>(c1, c2, a1, a2, b1, b2, rowbuf);
  diag_imm<<<1024, 256, 0, stream>>>(a1, a2, b1, b2, rowbuf);
  diag_pipe<<<4096, 256, 0, stream>>>(a1, a2, b1, b2, rowbuf);
  loss_final<<<1, 1024, 0, stream>>>(rowbuf, out);
}

// Round 13
// 30.629 us; speedup vs baseline: 7.7432x; 7.7432x over previous
//
#include <hip/hip_runtime.h>

// Chamfer via MFMA, round 13: FUSED pipeline (3 dispatches, no atomics).
// Round-12 diagnostic: main = 14.9us (MfmaUtil 52% = matrix-pipe floor 6.9us
// fully issued; VALU 61% co-busy), aux+gaps were ~16us of round-10's 31.4.
// This round harvests the aux+gaps:
//  - prep fused into main: A-frags built in regs, B-rep built in LDS from raw
//    floats (no 8MB rep round-trip, no prep dispatch/gap)
//  - no atomics/init: block (dir,b,ig,jc) direct-stores its 128-query partial
//    max into rowbuf slice [jc] (every slot written every call, deterministic)
//  - loss: 64-block slice-max+reduce -> 64 partials -> 1-wave finish
//  - j-loop fully unrolled: ds_read_b128 offset:imm, no addr VALU, no movs
// Swapped-operand MFMA (lane=query, regs=16 targets) + in-reg max3 tree.
// bf16 hi/lo rep (validated rounds 3-12, absmax 0):
//   A(q) = [qh(3), ql(3), qh(3), hq_h, hq_l,  1,  1, 0,0,0]
//   B(t) = [th(3), th(3), tl(3),  -1,  -1, -ht_h, -ht_l, 0,0,0]

#define NPTS    8192
#define BATCH   4
#define NJ      16
#define JCHUNK  512                // targets per block: 16 tiles, 16 KB LDS
#define JTILES  16
#define NSLOTS  (2 * BATCH * NPTS) // 65536

typedef __attribute__((ext_vector_type(8))) short short8v;
typedef __attribute__((ext_vector_type(16))) float f32x16;

__device__ __forceinline__ unsigned short f2bf(float x) {   // RNE bf16
  unsigned u = __float_as_uint(x);
  unsigned r = u + 0x7FFFu + ((u >> 16) & 1u);
  return (unsigned short)(r >> 16);
}
__device__ __forceinline__ float bf2f(unsigned short b) {
  return __uint_as_float((unsigned)b << 16);
}

__device__ __forceinline__ float tree17(const f32x16& c, float m) {
  float t0 = fmaxf(fmaxf(c[0],  c[1]),  c[2]);    // v_max3_f32
  float t1 = fmaxf(fmaxf(c[3],  c[4]),  c[5]);
  float t2 = fmaxf(fmaxf(c[6],  c[7]),  c[8]);
  float t3 = fmaxf(fmaxf(c[9],  c[10]), c[11]);
  float t4 = fmaxf(fmaxf(c[12], c[13]), c[14]);
  float u0 = fmaxf(fmaxf(t0, t1), t2);
  float u1 = fmaxf(fmaxf(t3, t4), c[15]);
  return fmaxf(fmaxf(u0, u1), m);
}

// Build this lane's A-fragment (k-half h) for the query at src (3 floats).
__device__ __forceinline__ short8v make_afrag(const float* __restrict__ src, int h) {
  float x = src[0], y = src[1], z = src[2];
  unsigned short xh = f2bf(x), yh = f2bf(y), zh = f2bf(z);
  unsigned short xl = f2bf(x - bf2f(xh)), yl = f2bf(y - bf2f(yh)),
                 zl = f2bf(z - bf2f(zh));
  float hn = 0.5f * (x * x + y * y + z * z);
  unsigned short hh = f2bf(hn), hl = f2bf(hn - bf2f(hh));
  const unsigned short one = 0x3F80u;
  unsigned short lo[8] = {xh, yh, zh, xl, yl, zl, xh, yh};
  unsigned short hi[8] = {zh, hh, hl, one, one, 0, 0, 0};
  short8v r;
  #pragma unroll
  for (int i = 0; i < 8; ++i) r[i] = (short)(h ? hi[i] : lo[i]);
  return r;
}

// grid = 2(dir) x 4(b) x 16(ig: 512 queries) x 16(jc) = 2048 blocks x 4 waves.
// Wave owns 4 query-tiles (128 queries); block builds 512-target rep in LDS
// from raw floats and loops 16 target tiles (fully unrolled).
__global__ __launch_bounds__(256, 6) void chamfer_main(
    const float* __restrict__ c1, const float* __restrict__ c2,
    float* __restrict__ rowbuf) {
  __shared__ __align__(16) unsigned short sB[JCHUNK * 16];  // 16 KB

  int bid = blockIdx.x;
  int jc  = bid & 15;
  int ig  = (bid >> 4) & 15;
  int b   = (bid >> 8) & 3;
  int dir = bid >> 10;

  const float* Q = dir ? c2 : c1;   // queries (raw floats)
  const float* T = dir ? c1 : c2;   // targets (raw floats)

  int t = threadIdx.x, wave = t >> 6, lane = t & 63;
  int p = lane & 31, h = lane >> 5;

  // ---- build B-rep for 512 targets directly in LDS ----
  const unsigned short negone = 0xBF80u;
  #pragma unroll
  for (int s = 0; s < 2; ++s) {
    int j = t + s * 256;
    const float* src = T + ((size_t)b * NPTS + jc * JCHUNK + j) * 3;
    float x = src[0], y = src[1], z = src[2];
    unsigned short xh = f2bf(x), yh = f2bf(y), zh = f2bf(z);
    unsigned short xl = f2bf(x - bf2f(xh)), yl = f2bf(y - bf2f(yh)),
                   zl = f2bf(z - bf2f(zh));
    float hn = 0.5f * (x * x + y * y + z * z);
    unsigned short hh = f2bf(hn), hl = f2bf(hn - bf2f(hh));
    unsigned short vb[16] = {xh, yh, zh, xh, yh, zh, xl, yl, zl,
                             negone, negone,
                             (unsigned short)(hh ^ 0x8000u),
                             (unsigned short)(hl ^ 0x8000u), 0, 0, 0};
    // layout: byte = jt*1024 + h*512 + p*16
    char* dst = (char*)sB + (j >> 5) * 1024 + (j & 31) * 16;
    *(uint4*)dst         = *(const uint4*)&vb[0];
    *(uint4*)(dst + 512) = *(const uint4*)&vb[8];
  }

  // ---- build A-fragments (4 query tiles) in registers ----
  int q0 = ig * 512 + wave * 128;
  const float* qb = Q + ((size_t)b * NPTS + q0 + p) * 3;
  short8v aq0 = make_afrag(qb,            h);
  short8v aq1 = make_afrag(qb + 32 * 3,   h);
  short8v aq2 = make_afrag(qb + 64 * 3,   h);
  short8v aq3 = make_afrag(qb + 96 * 3,   h);

  f32x16 zero;
  #pragma unroll
  for (int i = 0; i < 16; ++i) zero[i] = 0.0f;
  float m0 = -3.4e38f, m1 = -3.4e38f, m2 = -3.4e38f, m3 = -3.4e38f;

  __syncthreads();

  const char* spBase = (const char*)sB + h * 512 + p * 16;  // conflict-free

  #pragma unroll
  for (int jt = 0; jt < JTILES; ++jt) {
    short8v bt = *(const short8v*)(const void*)(spBase + jt * 1024);
    // swapped operands: rows(regs)=targets, cols(lanes)=queries
    f32x16 c0 = __builtin_amdgcn_mfma_f32_32x32x16_bf16(bt, aq0, zero, 0, 0, 0);
    f32x16 c1 = __builtin_amdgcn_mfma_f32_32x32x16_bf16(bt, aq1, zero, 0, 0, 0);
    f32x16 c2 = __builtin_amdgcn_mfma_f32_32x32x16_bf16(bt, aq2, zero, 0, 0, 0);
    f32x16 c3 = __builtin_amdgcn_mfma_f32_32x32x16_bf16(bt, aq3, zero, 0, 0, 0);
    m0 = tree17(c0, m0);   // in-lane: 16 targets for THIS lane's query
    m1 = tree17(c1, m1);
    m2 = tree17(c2, m2);
    m3 = tree17(c3, m3);
  }

  // lane L and L^32 hold the two target-halves of the same query
  m0 = fmaxf(m0, __shfl_xor(m0, 32, 64));
  m1 = fmaxf(m1, __shfl_xor(m1, 32, 64));
  m2 = fmaxf(m2, __shfl_xor(m2, 32, 64));
  m3 = fmaxf(m3, __shfl_xor(m3, 32, 64));

  // direct store into this jc's private slice — no atomics, no init
  if (lane < 32) {
    float* rb = rowbuf + (size_t)jc * NSLOTS +
                ((size_t)dir * BATCH + b) * NPTS + q0;
    rb[p]      = m0;
    rb[32 + p] = m1;
    rb[64 + p] = m2;
    rb[96 + p] = m3;
  }
}

// 64 blocks x 256 threads: each thread folds 4 slots over the 16 jc slices.
__global__ __launch_bounds__(256) void loss_part(
    const float* __restrict__ rowbuf, float* __restrict__ partials) {
  int idx = blockIdx.x * 256 + threadIdx.x;   // 0..16383
  float s = 0.0f;
  #pragma unroll
  for (int i = 0; i < 4; ++i) {
    int slot = idx + i * 16384;
    float m = -3.4e38f;
    #pragma unroll
    for (int j = 0; j < NJ; ++j)
      m = fmaxf(m, rowbuf[(size_t)j * NSLOTS + slot]);
    s = fmaf(-2.0f, m, s);   // min squared distance for this slot
  }
  #pragma unroll
  for (int off = 32; off > 0; off >>= 1) s += __shfl_down(s, off, 64);
  __shared__ float wsum[4];
  if ((threadIdx.x & 63) == 0) wsum[threadIdx.x >> 6] = s;
  __syncthreads();
  if (threadIdx.x == 0)
    partials[blockIdx.x] = (wsum[0] + wsum[1]) + (wsum[2] + wsum[3]);
}

__global__ __launch_bounds__(64) void loss_fin(
    const float* __restrict__ partials, float* __restrict__ out) {
  float s = partials[threadIdx.x];   // 64 partials, 1 wave
  #pragma unroll
  for (int off = 32; off > 0; off >>= 1) s += __shfl_down(s, off, 64);
  if (threadIdx.x == 0) out[0] = s;
}

extern "C" void kernel_launch(void* const* d_in, const int* in_sizes, int n_in,
                              void* d_out, int out_size, void* d_ws, size_t ws_size,
                              hipStream_t stream) {
  const float* c1 = (const float*)d_in[0];
  const float* c2 = (const float*)d_in[1];
  float* out = (float*)d_out;

  char* ws = (char*)d_ws;
  float* rowbuf = (float*)ws;                                  // 16 x 65536 f32 = 4 MB
  float* partials = (float*)(ws + (size_t)NJ * NSLOTS * 4);    // 64 f32

  chamfer_main<<<2 * BATCH * 16 * NJ, 256, 0, stream>>>(c1, c2, rowbuf);
  loss_part<<<64, 256, 0, stream>>>(rowbuf, partials);
  loss_fin<<<1, 64, 0, stream>>>(partials, out);
}